// Round 5
// baseline (57.843 us; speedup 1.0000x reference)
//
#include <hip/hip_runtime.h>
#include <math.h>

#define NROWS 65536
#define DDIM 512
#define NUM_CLASSES 1000
#define ROWS_PER_WAVE 8
#define NBLOCKS (NROWS / (ROWS_PER_WAVE * 4))   // 2048 blocks * 4 waves * 8 rows

__device__ inline float sqdiff4(float4 a, float4 b) {
    float dx = a.x - b.x, dy = a.y - b.y, dz = a.z - b.z, dw = a.w - b.w;
    return fmaf(dx, dx, fmaf(dy, dy, fmaf(dz, dz, dw * dw)));
}

// ws[0..999]  : per-class bins (f32, atomicAdd targets)
// ws[1000]    : completion counter (int)
// Zeroed each call by the hipMemsetAsync node.
//
// R2 lesson: NO __threadfence / ACQ_REL per block (L2 writeback storm).
// All bin updates are device-scope atomics -> they commit at the coherence
// point and leave no dirty L2 lines. So release only needs the wave-local
// s_waitcnt vmcnt(0), and the counter RMW + bin re-reads use RELAXED
// atomics (coherent path, no cache maintenance).
__global__ __launch_bounds__(256) void CenterLoss_fused(
    const float* __restrict__ x,
    const int* __restrict__ labels,
    const float* __restrict__ centers,
    float* __restrict__ ws,
    float* __restrict__ out)
{
    const int lane = threadIdx.x & 63;
    const int wid  = (blockIdx.x << 2) + (threadIdx.x >> 6);
    const int row0 = wid * ROWS_PER_WAVE;

#pragma unroll
    for (int half = 0; half < 2; ++half) {
        const int r = row0 + half * 4;

        const int l0 = labels[r + 0];
        const int l1 = labels[r + 1];
        const int l2 = labels[r + 2];
        const int l3 = labels[r + 3];

        const float4* __restrict__ x0 = (const float4*)(x + (size_t)(r + 0) * DDIM);
        const float4* __restrict__ x1 = (const float4*)(x + (size_t)(r + 1) * DDIM);
        const float4* __restrict__ x2 = (const float4*)(x + (size_t)(r + 2) * DDIM);
        const float4* __restrict__ x3 = (const float4*)(x + (size_t)(r + 3) * DDIM);
        const float4* __restrict__ c0 = (const float4*)(centers + (size_t)l0 * DDIM);
        const float4* __restrict__ c1 = (const float4*)(centers + (size_t)l1 * DDIM);
        const float4* __restrict__ c2 = (const float4*)(centers + (size_t)l2 * DDIM);
        const float4* __restrict__ c3 = (const float4*)(centers + (size_t)l3 * DDIM);

        const float4 xa0 = x0[lane], xb0 = x0[lane + 64];
        const float4 xa1 = x1[lane], xb1 = x1[lane + 64];
        const float4 xa2 = x2[lane], xb2 = x2[lane + 64];
        const float4 xa3 = x3[lane], xb3 = x3[lane + 64];
        const float4 ca0 = c0[lane], cb0 = c0[lane + 64];
        const float4 ca1 = c1[lane], cb1 = c1[lane + 64];
        const float4 ca2 = c2[lane], cb2 = c2[lane + 64];
        const float4 ca3 = c3[lane], cb3 = c3[lane + 64];

        float a0 = sqdiff4(xa0, ca0) + sqdiff4(xb0, cb0);
        float a1 = sqdiff4(xa1, ca1) + sqdiff4(xb1, cb1);
        float a2 = sqdiff4(xa2, ca2) + sqdiff4(xb2, cb2);
        float a3 = sqdiff4(xa3, ca3) + sqdiff4(xb3, cb3);

#pragma unroll
        for (int off = 32; off > 0; off >>= 1) {
            a0 += __shfl_xor(a0, off, 64);
            a1 += __shfl_xor(a1, off, 64);
            a2 += __shfl_xor(a2, off, 64);
            a3 += __shfl_xor(a3, off, 64);
        }

        const float av = (lane == 0) ? a0 : (lane == 1) ? a1 : (lane == 2) ? a2 : a3;
        const int   ab = (lane == 0) ? l0 : (lane == 1) ? l1 : (lane == 2) ? l2 : l3;
        if (lane < 4) atomicAdd(&ws[ab], av);
    }

    // ---- fused finalize, fence-free ----
    // wave-local: my bin atomics have reached the coherence point
    asm volatile("s_waitcnt vmcnt(0)" ::: "memory");
    __syncthreads();   // all 4 waves of this block done

    __shared__ int lastflag;
    if (threadIdx.x == 0) {
        int* counter = reinterpret_cast<int*>(ws + NUM_CLASSES);
        int prev = __hip_atomic_fetch_add(counter, 1, __ATOMIC_RELAXED,
                                          __HIP_MEMORY_SCOPE_AGENT);
        lastflag = (prev == NBLOCKS - 1) ? 1 : 0;
    }
    __syncthreads();
    if (!lastflag) return;

    // last block standing: all bins final at coherence point
    const int t = threadIdx.x;
    float s = 0.0f;
#pragma unroll
    for (int c = t; c < NUM_CLASSES; c += 256) {
        float v = __hip_atomic_load(&ws[c], __ATOMIC_RELAXED,
                                    __HIP_MEMORY_SCOPE_AGENT);
        s += sqrtf(v);
    }
#pragma unroll
    for (int off = 32; off > 0; off >>= 1)
        s += __shfl_xor(s, off, 64);

    __shared__ float partial[4];
    if (lane == 0) partial[t >> 6] = s;
    __syncthreads();
    if (t == 0)
        out[0] = (partial[0] + partial[1] + partial[2] + partial[3])
                 / (float)NUM_CLASSES;
}

extern "C" void kernel_launch(void* const* d_in, const int* in_sizes, int n_in,
                              void* d_out, int out_size, void* d_ws, size_t ws_size,
                              hipStream_t stream) {
    const float* x       = (const float*)d_in[0];
    const int*   labels  = (const int*)d_in[1];
    const float* centers = (const float*)d_in[2];
    float* out = (float*)d_out;
    float* ws  = (float*)d_ws;

    // zero bins + counter (memset node: cheap DMA, graph-capturable)
    hipMemsetAsync(ws, 0, 4096, stream);
    CenterLoss_fused<<<NBLOCKS, 256, 0, stream>>>(x, labels, centers, ws, out);
}

// Round 6
// 53.348 us; speedup vs baseline: 1.0843x; 1.0843x over previous
//
#include <hip/hip_runtime.h>
#include <math.h>

#define NROWS 65536
#define DDIM 512
#define NUM_CLASSES 1000

// ---------------- primary path: no global atomics, no zero pass ----------------
// accum: 256 blocks x 1024 threads (16 waves). Block b owns rows
// [b*256, b*256+256), accumulates squared distances into LDS bins[1000]
// (block-local ds_add_f32), then plain-stores its partial to ws[b*1024 + c].
// No global state is read before being written this call -> no init needed.

#define NB 256                     // partial slices
#define ROWS_PER_BLOCK (NROWS / NB)        // 256
#define WS_NEED ((size_t)NB * 1024 * 4)    // 1 MiB

__device__ inline float sqdiff4(float4 a, float4 b) {
    float dx = a.x - b.x, dy = a.y - b.y, dz = a.z - b.z, dw = a.w - b.w;
    return fmaf(dx, dx, fmaf(dy, dy, fmaf(dz, dz, dw * dw)));
}

__global__ __launch_bounds__(1024) void CenterLoss_accum_lds(
    const float* __restrict__ x,
    const int* __restrict__ labels,
    const float* __restrict__ centers,
    float* __restrict__ ws)
{
    __shared__ float bins[1000];
    const int t    = threadIdx.x;
    const int lane = t & 63;
    const int wave = t >> 6;               // 0..15

    if (t < 1000) bins[t] = 0.0f;
    __syncthreads();

    // wave handles 16 rows in 4 chunks of 4
    const int rowbase = blockIdx.x * ROWS_PER_BLOCK + wave * 16;

#pragma unroll
    for (int chunk = 0; chunk < 4; ++chunk) {
        const int r = rowbase + chunk * 4;

        const int l0 = labels[r + 0];
        const int l1 = labels[r + 1];
        const int l2 = labels[r + 2];
        const int l3 = labels[r + 3];

        const float4* __restrict__ x0 = (const float4*)(x + (size_t)(r + 0) * DDIM);
        const float4* __restrict__ x1 = (const float4*)(x + (size_t)(r + 1) * DDIM);
        const float4* __restrict__ x2 = (const float4*)(x + (size_t)(r + 2) * DDIM);
        const float4* __restrict__ x3 = (const float4*)(x + (size_t)(r + 3) * DDIM);
        const float4* __restrict__ c0 = (const float4*)(centers + (size_t)l0 * DDIM);
        const float4* __restrict__ c1 = (const float4*)(centers + (size_t)l1 * DDIM);
        const float4* __restrict__ c2 = (const float4*)(centers + (size_t)l2 * DDIM);
        const float4* __restrict__ c3 = (const float4*)(centers + (size_t)l3 * DDIM);

        const float4 xa0 = x0[lane], xb0 = x0[lane + 64];
        const float4 xa1 = x1[lane], xb1 = x1[lane + 64];
        const float4 xa2 = x2[lane], xb2 = x2[lane + 64];
        const float4 xa3 = x3[lane], xb3 = x3[lane + 64];
        const float4 ca0 = c0[lane], cb0 = c0[lane + 64];
        const float4 ca1 = c1[lane], cb1 = c1[lane + 64];
        const float4 ca2 = c2[lane], cb2 = c2[lane + 64];
        const float4 ca3 = c3[lane], cb3 = c3[lane + 64];

        float a0 = sqdiff4(xa0, ca0) + sqdiff4(xb0, cb0);
        float a1 = sqdiff4(xa1, ca1) + sqdiff4(xb1, cb1);
        float a2 = sqdiff4(xa2, ca2) + sqdiff4(xb2, cb2);
        float a3 = sqdiff4(xa3, ca3) + sqdiff4(xb3, cb3);

#pragma unroll
        for (int off = 32; off > 0; off >>= 1) {
            a0 += __shfl_xor(a0, off, 64);
            a1 += __shfl_xor(a1, off, 64);
            a2 += __shfl_xor(a2, off, 64);
            a3 += __shfl_xor(a3, off, 64);
        }

        const float av = (lane == 0) ? a0 : (lane == 1) ? a1 : (lane == 2) ? a2 : a3;
        const int   ab = (lane == 0) ? l0 : (lane == 1) ? l1 : (lane == 2) ? l2 : l3;
        if (lane < 4) atomicAdd(&bins[ab], av);   // block-local LDS atomic
    }

    __syncthreads();
    if (t < 1000) ws[(size_t)blockIdx.x * 1024 + t] = bins[t];  // coalesced
}

// finalize: thread t sums class t across the NB partials (coalesced wave
// loads, stride 4 KiB per step), sqrt, block-reduce, scale.
__global__ __launch_bounds__(1024) void CenterLoss_final_lds(
    const float* __restrict__ ws, float* __restrict__ out)
{
    const int t = threadIdx.x;
    const int lane = t & 63;

    float s0 = 0.f, s1 = 0.f, s2 = 0.f, s3 = 0.f;
    if (t < 1000) {
#pragma unroll 8
        for (int p = 0; p < NB; p += 4) {
            s0 += ws[(size_t)(p + 0) * 1024 + t];
            s1 += ws[(size_t)(p + 1) * 1024 + t];
            s2 += ws[(size_t)(p + 2) * 1024 + t];
            s3 += ws[(size_t)(p + 3) * 1024 + t];
        }
    }
    float s = (t < 1000) ? sqrtf((s0 + s1) + (s2 + s3)) : 0.0f;

#pragma unroll
    for (int off = 32; off > 0; off >>= 1)
        s += __shfl_xor(s, off, 64);

    __shared__ float partial[16];
    if (lane == 0) partial[t >> 6] = s;
    __syncthreads();
    if (t == 0) {
        float tot = 0.f;
#pragma unroll
        for (int w = 0; w < 16; ++w) tot += partial[w];
        out[0] = tot / (float)NUM_CLASSES;
    }
}

// ---------------- fallback path (proven R3): used only if ws too small --------
__global__ __launch_bounds__(256) void CenterLoss_zero_ws(float* __restrict__ ws) {
    for (int i = threadIdx.x; i < NUM_CLASSES; i += 256) ws[i] = 0.0f;
}

__global__ __launch_bounds__(256) void CenterLoss_accum_atomic(
    const float* __restrict__ x,
    const int* __restrict__ labels,
    const float* __restrict__ centers,
    float* __restrict__ ws)
{
    const int wave = threadIdx.x >> 6;
    const int lane = threadIdx.x & 63;
    const int row  = (blockIdx.x << 2) + wave;
    const int lbl  = labels[row];

    const float4* __restrict__ xr = (const float4*)(x + (size_t)row * DDIM);
    const float4* __restrict__ cr = (const float4*)(centers + (size_t)lbl * DDIM);

    const float4 xv0 = xr[lane], xv1 = xr[lane + 64];
    const float4 cv0 = cr[lane], cv1 = cr[lane + 64];
    float acc = sqdiff4(xv0, cv0) + sqdiff4(xv1, cv1);

#pragma unroll
    for (int off = 32; off > 0; off >>= 1)
        acc += __shfl_xor(acc, off, 64);

    if (lane == 0) atomicAdd(&ws[lbl], acc);
}

__global__ __launch_bounds__(256) void CenterLoss_final_atomic(
    const float* __restrict__ ws, float* __restrict__ out)
{
    const int t = threadIdx.x;
    const int lane = t & 63;
    float s = 0.0f;
    if (t < NUM_CLASSES / 4) {
        float4 v = reinterpret_cast<const float4*>(ws)[t];
        s = sqrtf(v.x) + sqrtf(v.y) + sqrtf(v.z) + sqrtf(v.w);
    }
#pragma unroll
    for (int off = 32; off > 0; off >>= 1)
        s += __shfl_xor(s, off, 64);
    __shared__ float partial[4];
    if (lane == 0) partial[t >> 6] = s;
    __syncthreads();
    if (t == 0)
        out[0] = (partial[0] + partial[1] + partial[2] + partial[3])
                 / (float)NUM_CLASSES;
}

extern "C" void kernel_launch(void* const* d_in, const int* in_sizes, int n_in,
                              void* d_out, int out_size, void* d_ws, size_t ws_size,
                              hipStream_t stream) {
    const float* x       = (const float*)d_in[0];
    const int*   labels  = (const int*)d_in[1];
    const float* centers = (const float*)d_in[2];
    float* out = (float*)d_out;
    float* ws  = (float*)d_ws;

    if (ws_size >= WS_NEED) {
        CenterLoss_accum_lds<<<NB, 1024, 0, stream>>>(x, labels, centers, ws);
        CenterLoss_final_lds<<<1, 1024, 0, stream>>>(ws, out);
    } else {
        CenterLoss_zero_ws<<<1, 256, 0, stream>>>(ws);
        CenterLoss_accum_atomic<<<NROWS / 4, 256, 0, stream>>>(x, labels, centers, ws);
        CenterLoss_final_atomic<<<1, 256, 0, stream>>>(ws, out);
    }
}